// Round 8
// baseline (75.535 us; speedup 1.0000x reference)
//
#include <hip/hip_runtime.h>

// query_depth_point: B=8, N=16384, M=2048, NSAMPLE=64, DIS_Z=0.5
// Persistent wave-per-4-queries: 4096 waves (1024 blocks x 256), all
// co-resident (16 waves/CU). Each wave owns 4 consecutive queries (always in
// the same batch since 4 | 2048) and scans the shared z1 row ONCE per
// 512-candidate chunk (8 floats/lane, candidate = c + 8*lane + j,
// lexicographic in (lane, j)), testing against 4 zq values. Per-query
// ordered rank via ballots + prefix popcount; per-query early exit at 64.
// Outer loop pinned `#pragma unroll 1`: 32-trip constant-bound loop with a
// large 4x-unrolled body -- full unroll would explode compile time.
// Outputs int32: idx (B,M,64) then pts_cnt (B,M).
// NOTE: timed window includes ~41.5 us of harness d_ws re-poison fill.

#define QDP_B 8
#define QDP_N 16384
#define QDP_M 2048
#define QDP_NS 64
#define QDP_DISZ 0.5f
#define QDP_QPW 4    // queries per wave

__global__ __launch_bounds__(256) void QueryDepthPoint_kernel(
    const float* __restrict__ xyz1,   // (B,3,N)
    const float* __restrict__ xyz2,   // (B,3,M)
    int* __restrict__ out_idx,        // (B,M,NS) int32
    int* __restrict__ out_cnt)        // (B,M)    int32
{
    const int lane = threadIdx.x & 63;
    const int wgid = (blockIdx.x << 2) + (threadIdx.x >> 6);   // 0..4095
    const unsigned long long below = (1ull << lane) - 1ull;

    const int qbase = wgid * QDP_QPW;           // first of 4 consecutive queries
    const int b = qbase >> 11;                  // same batch for all 4 (4 | 2048)
    const float* __restrict__ z1 = xyz1 + b * 3 * QDP_N + 2 * QDP_N;
    const float* __restrict__ z2 = xyz2 + b * 3 * QDP_M + 2 * QDP_M;

    float zq[QDP_QPW];
    int   cnt[QDP_QPW];
    int   firstv[QDP_QPW];
    #pragma unroll
    for (int k = 0; k < QDP_QPW; ++k) {
        zq[k]     = z2[(qbase & (QDP_M - 1)) + k];
        cnt[k]    = 0;
        firstv[k] = 0;
    }

    unsigned alive = (1u << QDP_QPW) - 1u;      // wave-uniform per-query active bits

    // prefetch chunk 0: lane covers candidates 8*lane .. 8*lane+7
    const float* lptr = z1 + 8 * lane;
    float4 curA = ((const float4*)lptr)[0];
    float4 curB = ((const float4*)lptr)[1];

    #pragma unroll 1   // do NOT unroll: 32 trips x large body = compile blowup
    for (int c = 0; c < QDP_N; c += 512) {
        const int pc = (c + 512 < QDP_N) ? (c + 512) : 0;  // clamped; unused on last iter
        const float* nptr = z1 + pc + 8 * lane;
        float4 nxtA = ((const float4*)nptr)[0];
        float4 nxtB = ((const float4*)nptr)[1];

        #pragma unroll
        for (int k = 0; k < QDP_QPW; ++k) {
            if (alive & (1u << k)) {                       // wave-uniform
                const float z = zq[k];
                const bool m0 = fabsf(curA.x - z) < QDP_DISZ;
                const bool m1 = fabsf(curA.y - z) < QDP_DISZ;
                const bool m2 = fabsf(curA.z - z) < QDP_DISZ;
                const bool m3 = fabsf(curA.w - z) < QDP_DISZ;
                const bool m4 = fabsf(curB.x - z) < QDP_DISZ;
                const bool m5 = fabsf(curB.y - z) < QDP_DISZ;
                const bool m6 = fabsf(curB.z - z) < QDP_DISZ;
                const bool m7 = fabsf(curB.w - z) < QDP_DISZ;

                const unsigned long long b0 = __ballot(m0);
                const unsigned long long b1 = __ballot(m1);
                const unsigned long long b2 = __ballot(m2);
                const unsigned long long b3 = __ballot(m3);
                const unsigned long long b4 = __ballot(m4);
                const unsigned long long b5 = __ballot(m5);
                const unsigned long long b6 = __ballot(m6);
                const unsigned long long b7 = __ballot(m7);
                const unsigned long long any = b0|b1|b2|b3|b4|b5|b6|b7;

                if (any) {                                  // wave-uniform
                    int* __restrict__ idx_out = out_idx + (size_t)(qbase + k) * QDP_NS;
                    const int mbyte = (int)m0 | ((int)m1<<1) | ((int)m2<<2) | ((int)m3<<3)
                                    | ((int)m4<<4) | ((int)m5<<5) | ((int)m6<<6) | ((int)m7<<7);
                    if (cnt[k] == 0) {
                        const int l0  = (int)__builtin_ctzll(any);
                        const int mb0 = __shfl(mbyte, l0);
                        firstv[k] = c + 8 * l0 + (int)__builtin_ctz((unsigned)mb0);
                    }
                    int r = cnt[k] + __popcll(b0 & below) + __popcll(b1 & below)
                                   + __popcll(b2 & below) + __popcll(b3 & below)
                                   + __popcll(b4 & below) + __popcll(b5 & below)
                                   + __popcll(b6 & below) + __popcll(b7 & below);
                    const int base = c + 8 * lane;
                    if (m0) { if (r < QDP_NS) idx_out[r] = base + 0; r++; }
                    if (m1) { if (r < QDP_NS) idx_out[r] = base + 1; r++; }
                    if (m2) { if (r < QDP_NS) idx_out[r] = base + 2; r++; }
                    if (m3) { if (r < QDP_NS) idx_out[r] = base + 3; r++; }
                    if (m4) { if (r < QDP_NS) idx_out[r] = base + 4; r++; }
                    if (m5) { if (r < QDP_NS) idx_out[r] = base + 5; r++; }
                    if (m6) { if (r < QDP_NS) idx_out[r] = base + 6; r++; }
                    if (m7) { if (r < QDP_NS) idx_out[r] = base + 7; r++; }
                    cnt[k] += __popcll(b0) + __popcll(b1) + __popcll(b2) + __popcll(b3)
                            + __popcll(b4) + __popcll(b5) + __popcll(b6) + __popcll(b7);
                    if (cnt[k] >= QDP_NS) { cnt[k] = QDP_NS; alive &= ~(1u << k); }
                }
            }
        }
        if (!alive) break;                                  // all 4 queries done
        curA = nxtA; curB = nxtB;
    }

    // epilogue: trailing slots [cnt, 64) get first-match index (0 if none)
    #pragma unroll
    for (int k = 0; k < QDP_QPW; ++k) {
        int* __restrict__ idx_out = out_idx + (size_t)(qbase + k) * QDP_NS;
        if (lane >= cnt[k]) idx_out[lane] = firstv[k];
        if (lane == 0)      out_cnt[qbase + k] = cnt[k];
    }
}

extern "C" void kernel_launch(void* const* d_in, const int* in_sizes, int n_in,
                              void* d_out, int out_size, void* d_ws, size_t ws_size,
                              hipStream_t stream) {
    const float* xyz1 = (const float*)d_in[0];   // (B,3,N) fp32
    const float* xyz2 = (const float*)d_in[1];   // (B,3,M) fp32
    int* out = (int*)d_out;                      // idx (B*M*64) then pts_cnt (B*M)

    int* out_idx = out;
    int* out_cnt = out + (size_t)QDP_B * QDP_M * QDP_NS;

    // 4096 waves x 4 queries = 16384 queries; 1024 blocks x 256 threads
    // = 4 blocks/CU = 16 waves/CU -> fully co-resident, no ramp/refill.
    QueryDepthPoint_kernel<<<1024, 256, 0, stream>>>(xyz1, xyz2, out_idx, out_cnt);
}